// Round 9
// baseline (234.316 us; speedup 1.0000x reference)
//
#include <hip/hip_runtime.h>
#include <hip/hip_bf16.h>
#include <math.h>

#define HW2 262144              // 512*512
#define TWO_PI     6.28318530717958647693f
#define INV_TWO_PI 0.15915494309189533577f
#define LOG2E      1.44269504088896340736f

typedef float  f32x4  __attribute__((ext_vector_type(4)));
typedef short  s16x8  __attribute__((ext_vector_type(8)));
typedef unsigned short ushort_t;

__device__ __forceinline__ ushort_t bf16_hi(float v) {
    __hip_bfloat16 h = __float2bfloat16(v);
    return __builtin_bit_cast(ushort_t, h);
}
__device__ __forceinline__ float bf16_tof(ushort_t u) {
    unsigned int x = ((unsigned int)u) << 16;
    return __builtin_bit_cast(float, x);
}

// k-slot permutation (verified R7/R8, absmax 6.1e-5): stored k-slot
// (KC*32 + g*8 + j) holds source channel KC*32 + (j>>2)*16 + g*4 + (j&3).
// With W columns stored in this order, next-layer B-frag elem j of chunk KC
// at lane-group g equals acc[2KC + (j>>2)][j&3] ON THE SAME LANE ->
// no LDS / shuffle / barrier relayout between layers.
__device__ __forceinline__ int kperm(int ks) {
    int KC = ks >> 5, g = (ks >> 3) & 3, j = ks & 7;
    return KC * 32 + (j >> 2) * 16 + g * 4 + (j & 3);
}

// ---- ws layout (bytes) ----
// pcq    f32[5][64][12] @ 0      expanded gabor constants
//   per channel: [a,b,c,d, e,f,w0r,w1r, br,0,0,0]
// whi    u16[4][64][64] @ 15360  lin_w hi-bf16, [c_out][k_perm]
// wlo    u16[4][64][64] @ 48128  lin_w lo-bf16
// wouthi u16[16][64]    @ 80896  out_w hi (rows 3..15 zero), k_perm cols
// woutlo u16[16][64]    @ 82944
#define WS_WHI  15360
#define WS_WLO  48128
#define WS_WOH  80896
#define WS_WOL  82944

__global__ void gabor_pre(const float* __restrict__ filt_w,
                          const float* __restrict__ filt_b,
                          const float* __restrict__ mu,
                          const float* __restrict__ gamma,
                          const float* __restrict__ theta,
                          const float* __restrict__ lin_w,
                          const float* __restrict__ out_w,
                          float* __restrict__ pcq,
                          ushort_t* __restrict__ whi, ushort_t* __restrict__ wlo,
                          ushort_t* __restrict__ wouthi, ushort_t* __restrict__ woutlo) {
    int t = blockIdx.x * 256 + threadIdx.x;
    if (t < 320) {
        int i = t;
        float ang = TWO_PI * theta[i];
        float cs = cosf(ang), sn = sinf(ang);
        float g0 = gamma[i*2+0], g1 = gamma[i*2+1];
        float g0s = g0*g0, g1s = g1*g1;
        float cs2 = cs*cs, sn2 = sn*sn;
        float A = -0.5f * LOG2E * (g0s*cs2 + g1s*sn2);
        float B = -LOG2E * (cs*sn*(g0s - g1s));
        float C = -0.5f * LOG2E * (g0s*sn2 + g1s*cs2);
        float m0 = mu[i*2+0], m1 = mu[i*2+1];
        float* o = pcq + i*12;
        o[0] = A;  o[1] = B;  o[2] = C;
        o[3] = -(2.0f*A*m0 + B*m1);
        o[4] = -(B*m0 + 2.0f*C*m1);
        o[5] = A*m0*m0 + B*m0*m1 + C*m1*m1;
        o[6] = filt_w[i*2+0] * INV_TWO_PI;
        o[7] = filt_w[i*2+1] * INV_TWO_PI;
        o[8] = filt_b[i] * INV_TWO_PI;
        o[9] = 0.0f; o[10] = 0.0f; o[11] = 0.0f;
    } else if (t < 320 + 16384) {
        int i  = t - 320;                      // l*4096 + c*64 + ks
        int ks = i & 63;
        float w = lin_w[(i - ks) + kperm(ks)];
        ushort_t h = bf16_hi(w);
        whi[i] = h;
        wlo[i] = bf16_hi(w - bf16_tof(h));
    } else if (t < 320 + 16384 + 1024) {
        int i  = t - (320 + 16384);            // m*64 + ks
        int m  = i >> 6, ks = i & 63;
        float w = (m < 3) ? out_w[m*64 + kperm(ks)] : 0.0f;
        ushort_t h = bf16_hi(w);
        wouthi[i] = h;
        woutlo[i] = bf16_hi(w - bf16_tof(h));
    }
}

// expanded gabor eval (x02,x11,x12 shared per pixel)
__device__ __forceinline__ float gevalp(const float* __restrict__ q,
                                        float x0, float x1,
                                        float x02, float x11, float x12) {
    f32x4 qa = *(const f32x4*)q;
    f32x4 qb = *(const f32x4*)(q + 4);
    float t = fmaf(qa[0], x02, fmaf(qa[1], x11,
              fmaf(qa[2], x12, fmaf(qa[3], x0, fmaf(qb[0], x1, qb[1])))));
    float e  = __builtin_amdgcn_exp2f(t);
    float sa = fmaf(qb[2], x0, fmaf(qb[3], x1, q[8]));
    return e * __builtin_amdgcn_sinf(sa);
}

// 4 consecutive channels starting at q (stride 12 floats)
__device__ __forceinline__ f32x4 geval4(const float* __restrict__ q,
                                        float x0, float x1,
                                        float x02, float x11, float x12) {
    f32x4 r;
    r[0] = gevalp(q,      x0, x1, x02, x11, x12);
    r[1] = gevalp(q + 12, x0, x1, x02, x11, x12);
    r[2] = gevalp(q + 24, x0, x1, x02, x11, x12);
    r[3] = gevalp(q + 36, x0, x1, x02, x11, x12);
    return r;
}

struct frag2 { s16x8 h, l; };
// build B-frag pair (hi/lo) from two C/D f32x4's (MI even, MI odd)
__device__ __forceinline__ frag2 mkfrag(f32x4 vA, f32x4 vB) {
    s16x8 fh, fl;
#define MKF_R(R) { \
    ushort_t hA = bf16_hi(vA[R]); ushort_t hB = bf16_hi(vB[R]); \
    fh[R] = (short)hA; fh[R + 4] = (short)hB; \
    fl[R]     = (short)bf16_hi(vA[R] - bf16_tof(hA)); \
    fl[R + 4] = (short)bf16_hi(vB[R] - bf16_tof(hB)); }
    MKF_R(0) MKF_R(1) MKF_R(2) MKF_R(3)
#undef MKF_R
    return {fh, fl};
}

// One wave = 32 pixels (NI=2), 4 independent waves per 256-block. No LDS,
// no barriers, no local arrays (R8 lesson). NI=4 (R8) held 64 frag regs +
// 64 acc regs -> ~192 total incl AGPR -> 1.7 waves/SIMD, VALUBusy 48%.
// NI=2 halves frag+acc state (~110-145 total) -> 3-4 waves/SIMD for
// latency hiding of gevalp dep chains + quarter-rate sin/exp.
// GEMM per layer: D[c,px] = W[c,k] h[k,px], mfma_f32_16x16x32_bf16,
// 3-product split-bf16 (ah*bh + ah*bl + al*bh; al*bl ~2^-18 dropped).
//   A frag: m = lane&15, k-slot = (lane>>4)*8 + j  (W rows, permuted cols)
//   B frag: n = lane&15 (pixel), k-slot = (lane>>4)*8 + j
//   C/D:    col n = lane&15 (pixel), row m = (lane>>4)*4 + reg (channel)
__global__ __launch_bounds__(256, 3) void gabor_mfma(
    const float* __restrict__ x, const float* __restrict__ lin_b,
    const float* __restrict__ out_b, const float* __restrict__ pcq,
    const ushort_t* __restrict__ whi, const ushort_t* __restrict__ wlo,
    const ushort_t* __restrict__ wouthi, const ushort_t* __restrict__ woutlo,
    float* __restrict__ out) {
    const int lane = threadIdx.x & 63;
    const int wid  = threadIdx.x >> 6;
    const int g    = lane >> 4;
    const int lm   = lane & 15;
    const int base = blockIdx.x * 128 + wid * 32;

    float x0_0, x1_0, x02_0, x11_0, x12_0;
    float x0_1, x1_1, x02_1, x11_1, x12_1;
    int pixo0, pixo1;
#define LOADPX(NI) { \
    int P = base + NI*16 + lm; \
    int bb = P >> 18, pix = P & (HW2 - 1); \
    const float* xb = x + bb*(2*HW2) + pix; \
    float a = xb[0], b = xb[HW2]; \
    x0_##NI = a; x1_##NI = b; \
    x02_##NI = a*a; x11_##NI = a*b; x12_##NI = b*b; \
    if (NI == 0) pixo0 = bb*(3*HW2) + pix; else pixo1 = bb*(3*HW2) + pix; }
    LOADPX(0) LOADPX(1)
#undef LOADPX

    // h as B-fragments: fh_<ni>_<kc> / fl_<ni>_<kc>, all named (no arrays)
    s16x8 fh_0_0, fh_0_1, fh_1_0, fh_1_1;
    s16x8 fl_0_0, fl_0_1, fl_1_0, fl_1_1;

    // ---- layer 0: gabor at C/D positions, straight into frags ----
#define L0(NI) { \
    f32x4 v0 = geval4(pcq + (4*g)*12,      x0_##NI, x1_##NI, x02_##NI, x11_##NI, x12_##NI); \
    f32x4 v1 = geval4(pcq + (16 + 4*g)*12, x0_##NI, x1_##NI, x02_##NI, x11_##NI, x12_##NI); \
    f32x4 v2 = geval4(pcq + (32 + 4*g)*12, x0_##NI, x1_##NI, x02_##NI, x11_##NI, x12_##NI); \
    f32x4 v3 = geval4(pcq + (48 + 4*g)*12, x0_##NI, x1_##NI, x02_##NI, x11_##NI, x12_##NI); \
    frag2 tA = mkfrag(v0, v1); frag2 tB = mkfrag(v2, v3); \
    fh_##NI##_0 = tA.h; fl_##NI##_0 = tA.l; \
    fh_##NI##_1 = tB.h; fl_##NI##_1 = tB.l; }
    L0(0) L0(1)
#undef L0

#define BMFMA __builtin_amdgcn_mfma_f32_16x16x32_bf16
    // ---- layers 1..4 ----
#pragma unroll 1
    for (int l = 1; l <= 4; ++l) {
        const ushort_t* whl = whi + (l-1)*4096;
        const ushort_t* wll = wlo + (l-1)*4096;
        const float*    bv  = lin_b + (l-1)*64;
        const float*    pcl = pcq + l*768;

        f32x4 bb0 = *(const f32x4*)(bv +      4*g);
        f32x4 bb1 = *(const f32x4*)(bv + 16 + 4*g);
        f32x4 bb2 = *(const f32x4*)(bv + 32 + 4*g);
        f32x4 bb3 = *(const f32x4*)(bv + 48 + 4*g);
        f32x4 a_0_0 = bb0, a_0_1 = bb0;
        f32x4 a_1_0 = bb1, a_1_1 = bb1;
        f32x4 a_2_0 = bb2, a_2_1 = bb2;
        f32x4 a_3_0 = bb3, a_3_1 = bb3;

        // each W fragment pair feeds both pixel tiles (6 MFMAs per load)
#define MSTEP(KC, MI) { \
        const s16x8 ah = *(const s16x8*)(whl + (MI*16 + lm)*64 + KC*32 + g*8); \
        const s16x8 al = *(const s16x8*)(wll + (MI*16 + lm)*64 + KC*32 + g*8); \
        a_##MI##_0 = BMFMA(ah, fh_0_##KC, a_##MI##_0, 0, 0, 0); \
        a_##MI##_0 = BMFMA(ah, fl_0_##KC, a_##MI##_0, 0, 0, 0); \
        a_##MI##_0 = BMFMA(al, fh_0_##KC, a_##MI##_0, 0, 0, 0); \
        a_##MI##_1 = BMFMA(ah, fh_1_##KC, a_##MI##_1, 0, 0, 0); \
        a_##MI##_1 = BMFMA(ah, fl_1_##KC, a_##MI##_1, 0, 0, 0); \
        a_##MI##_1 = BMFMA(al, fh_1_##KC, a_##MI##_1, 0, 0, 0); }
        MSTEP(0, 0) MSTEP(0, 1) MSTEP(0, 2) MSTEP(0, 3)
        MSTEP(1, 0) MSTEP(1, 1) MSTEP(1, 2) MSTEP(1, 3)
#undef MSTEP

        // epilogue: acc *= gabor (params CSE'd across the 2 pixel tiles)
#define EPI(MI) { \
        const float* qb_ = pcl + (MI*16 + 4*g)*12; \
        a_##MI##_0 *= geval4(qb_, x0_0, x1_0, x02_0, x11_0, x12_0); \
        a_##MI##_1 *= geval4(qb_, x0_1, x1_1, x02_1, x11_1, x12_1); }
        EPI(0) EPI(1) EPI(2) EPI(3)
#undef EPI

        // rebuild next-layer B-frags in-register (kperm identity)
#define REB(NI) { \
        frag2 tA = mkfrag(a_0_##NI, a_1_##NI); \
        frag2 tB = mkfrag(a_2_##NI, a_3_##NI); \
        fh_##NI##_0 = tA.h; fl_##NI##_0 = tA.l; \
        fh_##NI##_1 = tB.h; fl_##NI##_1 = tB.l; }
        REB(0) REB(1)
#undef REB
    }

    // ---- output: out[o,px] = Wout[o,k] h4[k,px] + out_b ----
    const s16x8 oh0 = *(const s16x8*)(wouthi + lm*64 +      g*8);
    const s16x8 ol0 = *(const s16x8*)(woutlo + lm*64 +      g*8);
    const s16x8 oh1 = *(const s16x8*)(wouthi + lm*64 + 32 + g*8);
    const s16x8 ol1 = *(const s16x8*)(woutlo + lm*64 + 32 + g*8);
    float ob0 = out_b[0], ob1 = out_b[1], ob2 = out_b[2];
#define OUTNI(NI, PO) { \
    f32x4 ao = (f32x4)(0.0f); \
    ao = BMFMA(oh0, fh_##NI##_0, ao, 0, 0, 0); \
    ao = BMFMA(oh0, fl_##NI##_0, ao, 0, 0, 0); \
    ao = BMFMA(ol0, fh_##NI##_0, ao, 0, 0, 0); \
    ao = BMFMA(oh1, fh_##NI##_1, ao, 0, 0, 0); \
    ao = BMFMA(oh1, fl_##NI##_1, ao, 0, 0, 0); \
    ao = BMFMA(ol1, fh_##NI##_1, ao, 0, 0, 0); \
    if (lane < 16) { \
        float* po = out + PO; \
        po[0]     = ao[0] + ob0; \
        po[HW2]   = ao[1] + ob1; \
        po[2*HW2] = ao[2] + ob2; } }
    OUTNI(0, pixo0) OUTNI(1, pixo1)
#undef OUTNI
#undef BMFMA
}

extern "C" void kernel_launch(void* const* d_in, const int* in_sizes, int n_in,
                              void* d_out, int out_size, void* d_ws, size_t ws_size,
                              hipStream_t stream) {
    const float* x      = (const float*)d_in[0];
    const float* filt_w = (const float*)d_in[1];
    const float* filt_b = (const float*)d_in[2];
    const float* mu     = (const float*)d_in[3];
    const float* gamma  = (const float*)d_in[4];
    const float* theta  = (const float*)d_in[5];
    const float* lin_w  = (const float*)d_in[6];
    const float* lin_b  = (const float*)d_in[7];
    const float* out_w  = (const float*)d_in[8];
    const float* out_b  = (const float*)d_in[9];

    char* ws = (char*)d_ws;
    float*    pcq    = (float*)ws;
    ushort_t* whi    = (ushort_t*)(ws + WS_WHI);
    ushort_t* wlo    = (ushort_t*)(ws + WS_WLO);
    ushort_t* wouthi = (ushort_t*)(ws + WS_WOH);
    ushort_t* woutlo = (ushort_t*)(ws + WS_WOL);

    gabor_pre<<<70, 256, 0, stream>>>(filt_w, filt_b, mu, gamma, theta,
                                      lin_w, out_w, pcq, whi, wlo, wouthi, woutlo);
    gabor_mfma<<<4096, 256, 0, stream>>>(x, lin_b, out_b, pcq, whi, wlo,
                                         wouthi, woutlo, (float*)d_out);
}

// Round 10
// 221.538 us; speedup vs baseline: 1.0577x; 1.0577x over previous
//
#include <hip/hip_runtime.h>
#include <hip/hip_bf16.h>
#include <math.h>

#define HW2 262144              // 512*512
#define TWO_PI     6.28318530717958647693f
#define INV_TWO_PI 0.15915494309189533577f
#define LOG2E      1.44269504088896340736f

typedef float  f32x4  __attribute__((ext_vector_type(4)));
typedef short  s16x8  __attribute__((ext_vector_type(8)));
typedef unsigned short ushort_t;

__device__ __forceinline__ ushort_t bf16_hi(float v) {
    __hip_bfloat16 h = __float2bfloat16(v);
    return __builtin_bit_cast(ushort_t, h);
}
__device__ __forceinline__ float bf16_tof(ushort_t u) {
    unsigned int x = ((unsigned int)u) << 16;
    return __builtin_bit_cast(float, x);
}

// k-slot permutation (verified R7/R8, absmax 6.1e-5): stored k-slot
// (KC*32 + g*8 + j) holds source channel KC*32 + (j>>2)*16 + g*4 + (j&3).
// With W columns stored in this order, next-layer B-frag elem j of chunk KC
// at lane-group g equals acc[2KC + (j>>2)][j&3] ON THE SAME LANE ->
// no LDS / shuffle / barrier relayout between layers.
__device__ __forceinline__ int kperm(int ks) {
    int KC = ks >> 5, g = (ks >> 3) & 3, j = ks & 7;
    return KC * 32 + (j >> 2) * 16 + g * 4 + (j & 3);
}

// ---- ws layout (bytes) ----
// pcq    f32[5][64][12] @ 0      expanded gabor constants
//   per channel: [a,b,c,d, e,f,w0r,w1r, br,0,0,0]
// whi    u16[4][64][64] @ 15360  lin_w hi-bf16, [c_out][k_perm]
// wlo    u16[4][64][64] @ 48128  lin_w lo-bf16
// wouthi u16[16][64]    @ 80896  out_w hi (rows 3..15 zero), k_perm cols
// woutlo u16[16][64]    @ 82944
#define WS_WHI  15360
#define WS_WLO  48128
#define WS_WOH  80896
#define WS_WOL  82944

__global__ void gabor_pre(const float* __restrict__ filt_w,
                          const float* __restrict__ filt_b,
                          const float* __restrict__ mu,
                          const float* __restrict__ gamma,
                          const float* __restrict__ theta,
                          const float* __restrict__ lin_w,
                          const float* __restrict__ out_w,
                          float* __restrict__ pcq,
                          ushort_t* __restrict__ whi, ushort_t* __restrict__ wlo,
                          ushort_t* __restrict__ wouthi, ushort_t* __restrict__ woutlo) {
    int t = blockIdx.x * 256 + threadIdx.x;
    if (t < 320) {
        int i = t;
        float ang = TWO_PI * theta[i];
        float cs = cosf(ang), sn = sinf(ang);
        float g0 = gamma[i*2+0], g1 = gamma[i*2+1];
        float g0s = g0*g0, g1s = g1*g1;
        float cs2 = cs*cs, sn2 = sn*sn;
        float A = -0.5f * LOG2E * (g0s*cs2 + g1s*sn2);
        float B = -LOG2E * (cs*sn*(g0s - g1s));
        float C = -0.5f * LOG2E * (g0s*sn2 + g1s*cs2);
        float m0 = mu[i*2+0], m1 = mu[i*2+1];
        float* o = pcq + i*12;
        o[0] = A;  o[1] = B;  o[2] = C;
        o[3] = -(2.0f*A*m0 + B*m1);
        o[4] = -(B*m0 + 2.0f*C*m1);
        o[5] = A*m0*m0 + B*m0*m1 + C*m1*m1;
        o[6] = filt_w[i*2+0] * INV_TWO_PI;
        o[7] = filt_w[i*2+1] * INV_TWO_PI;
        o[8] = filt_b[i] * INV_TWO_PI;
        o[9] = 0.0f; o[10] = 0.0f; o[11] = 0.0f;
    } else if (t < 320 + 16384) {
        int i  = t - 320;                      // l*4096 + c*64 + ks
        int ks = i & 63;
        float w = lin_w[(i - ks) + kperm(ks)];
        ushort_t h = bf16_hi(w);
        whi[i] = h;
        wlo[i] = bf16_hi(w - bf16_tof(h));
    } else if (t < 320 + 16384 + 1024) {
        int i  = t - (320 + 16384);            // m*64 + ks
        int m  = i >> 6, ks = i & 63;
        float w = (m < 3) ? out_w[m*64 + kperm(ks)] : 0.0f;
        ushort_t h = bf16_hi(w);
        wouthi[i] = h;
        woutlo[i] = bf16_hi(w - bf16_tof(h));
    }
}

// expanded gabor eval (x02,x11,x12 shared per pixel)
__device__ __forceinline__ float gevalp(const float* __restrict__ q,
                                        float x0, float x1,
                                        float x02, float x11, float x12) {
    f32x4 qa = *(const f32x4*)q;
    f32x4 qb = *(const f32x4*)(q + 4);
    float t = fmaf(qa[0], x02, fmaf(qa[1], x11,
              fmaf(qa[2], x12, fmaf(qa[3], x0, fmaf(qb[0], x1, qb[1])))));
    float e  = __builtin_amdgcn_exp2f(t);
    float sa = fmaf(qb[2], x0, fmaf(qb[3], x1, q[8]));
    return e * __builtin_amdgcn_sinf(sa);
}

// 4 consecutive channels starting at q (stride 12 floats)
__device__ __forceinline__ f32x4 geval4(const float* __restrict__ q,
                                        float x0, float x1,
                                        float x02, float x11, float x12) {
    f32x4 r;
    r[0] = gevalp(q,      x0, x1, x02, x11, x12);
    r[1] = gevalp(q + 12, x0, x1, x02, x11, x12);
    r[2] = gevalp(q + 24, x0, x1, x02, x11, x12);
    r[3] = gevalp(q + 36, x0, x1, x02, x11, x12);
    return r;
}

struct frag2 { s16x8 h, l; };
// build B-frag pair (hi/lo) from two C/D f32x4's (MI even, MI odd)
__device__ __forceinline__ frag2 mkfrag(f32x4 vA, f32x4 vB) {
    s16x8 fh, fl;
#define MKF_R(R) { \
    ushort_t hA = bf16_hi(vA[R]); ushort_t hB = bf16_hi(vB[R]); \
    fh[R] = (short)hA; fh[R + 4] = (short)hB; \
    fl[R]     = (short)bf16_hi(vA[R] - bf16_tof(hA)); \
    fl[R + 4] = (short)bf16_hi(vB[R] - bf16_tof(hB)); }
    MKF_R(0) MKF_R(1) MKF_R(2) MKF_R(3)
#undef MKF_R
    return {fh, fl};
}

// One wave = 32 pixels (NI=2), 4 independent waves per 256-block. No LDS,
// no barriers, no local arrays. launch_bounds(256,2): R9 showed (256,3)
// makes the allocator spill wholesale (VGPR 84 + 42MB scratch writes);
// (256,2) produced clean code at higher pressure (R8). NI=2 live state
// ~110 regs -> hoping allocator lands <=128 incl AGPR -> 4 waves/SIMD.
// GEMM per layer: D[c,px] = W[c,k] h[k,px], mfma_f32_16x16x32_bf16,
// 3-product split-bf16 (ah*bh + ah*bl + al*bh; al*bl ~2^-18 dropped).
//   A frag: m = lane&15, k-slot = (lane>>4)*8 + j  (W rows, permuted cols)
//   B frag: n = lane&15 (pixel), k-slot = (lane>>4)*8 + j
//   C/D:    col n = lane&15 (pixel), row m = (lane>>4)*4 + reg (channel)
__global__ __launch_bounds__(256, 2) void gabor_mfma(
    const float* __restrict__ x, const float* __restrict__ lin_b,
    const float* __restrict__ out_b, const float* __restrict__ pcq,
    const ushort_t* __restrict__ whi, const ushort_t* __restrict__ wlo,
    const ushort_t* __restrict__ wouthi, const ushort_t* __restrict__ woutlo,
    float* __restrict__ out) {
    const int lane = threadIdx.x & 63;
    const int wid  = threadIdx.x >> 6;
    const int g    = lane >> 4;
    const int lm   = lane & 15;
    const int base = blockIdx.x * 128 + wid * 32;

    float x0_0, x1_0, x02_0, x11_0, x12_0;
    float x0_1, x1_1, x02_1, x11_1, x12_1;
    int pixo0, pixo1;
#define LOADPX(NI) { \
    int P = base + NI*16 + lm; \
    int bb = P >> 18, pix = P & (HW2 - 1); \
    const float* xb = x + bb*(2*HW2) + pix; \
    float a = xb[0], b = xb[HW2]; \
    x0_##NI = a; x1_##NI = b; \
    x02_##NI = a*a; x11_##NI = a*b; x12_##NI = b*b; \
    if (NI == 0) pixo0 = bb*(3*HW2) + pix; else pixo1 = bb*(3*HW2) + pix; }
    LOADPX(0) LOADPX(1)
#undef LOADPX

    // h as B-fragments: fh_<ni>_<kc> / fl_<ni>_<kc>, all named (no arrays)
    s16x8 fh_0_0, fh_0_1, fh_1_0, fh_1_1;
    s16x8 fl_0_0, fl_0_1, fl_1_0, fl_1_1;

    // ---- layer 0: gabor at C/D positions, straight into frags ----
#define L0(NI) { \
    f32x4 v0 = geval4(pcq + (4*g)*12,      x0_##NI, x1_##NI, x02_##NI, x11_##NI, x12_##NI); \
    f32x4 v1 = geval4(pcq + (16 + 4*g)*12, x0_##NI, x1_##NI, x02_##NI, x11_##NI, x12_##NI); \
    f32x4 v2 = geval4(pcq + (32 + 4*g)*12, x0_##NI, x1_##NI, x02_##NI, x11_##NI, x12_##NI); \
    f32x4 v3 = geval4(pcq + (48 + 4*g)*12, x0_##NI, x1_##NI, x02_##NI, x11_##NI, x12_##NI); \
    frag2 tA = mkfrag(v0, v1); frag2 tB = mkfrag(v2, v3); \
    fh_##NI##_0 = tA.h; fl_##NI##_0 = tA.l; \
    fh_##NI##_1 = tB.h; fl_##NI##_1 = tB.l; }
    L0(0) L0(1)
#undef L0

#define BMFMA __builtin_amdgcn_mfma_f32_16x16x32_bf16
    // ---- layers 1..4 ----
#pragma unroll 1
    for (int l = 1; l <= 4; ++l) {
        const ushort_t* whl = whi + (l-1)*4096;
        const ushort_t* wll = wlo + (l-1)*4096;
        const float*    bv  = lin_b + (l-1)*64;
        const float*    pcl = pcq + l*768;

        f32x4 bb0 = *(const f32x4*)(bv +      4*g);
        f32x4 bb1 = *(const f32x4*)(bv + 16 + 4*g);
        f32x4 bb2 = *(const f32x4*)(bv + 32 + 4*g);
        f32x4 bb3 = *(const f32x4*)(bv + 48 + 4*g);
        f32x4 a_0_0 = bb0, a_0_1 = bb0;
        f32x4 a_1_0 = bb1, a_1_1 = bb1;
        f32x4 a_2_0 = bb2, a_2_1 = bb2;
        f32x4 a_3_0 = bb3, a_3_1 = bb3;

        // each W fragment pair feeds both pixel tiles (6 MFMAs per load)
#define MSTEP(KC, MI) { \
        const s16x8 ah = *(const s16x8*)(whl + (MI*16 + lm)*64 + KC*32 + g*8); \
        const s16x8 al = *(const s16x8*)(wll + (MI*16 + lm)*64 + KC*32 + g*8); \
        a_##MI##_0 = BMFMA(ah, fh_0_##KC, a_##MI##_0, 0, 0, 0); \
        a_##MI##_0 = BMFMA(ah, fl_0_##KC, a_##MI##_0, 0, 0, 0); \
        a_##MI##_0 = BMFMA(al, fh_0_##KC, a_##MI##_0, 0, 0, 0); \
        a_##MI##_1 = BMFMA(ah, fh_1_##KC, a_##MI##_1, 0, 0, 0); \
        a_##MI##_1 = BMFMA(ah, fl_1_##KC, a_##MI##_1, 0, 0, 0); \
        a_##MI##_1 = BMFMA(al, fh_1_##KC, a_##MI##_1, 0, 0, 0); }
        MSTEP(0, 0) MSTEP(0, 1) MSTEP(0, 2) MSTEP(0, 3)
        MSTEP(1, 0) MSTEP(1, 1) MSTEP(1, 2) MSTEP(1, 3)
#undef MSTEP

        // epilogue: acc *= gabor (params CSE'd across the 2 pixel tiles)
#define EPI(MI) { \
        const float* qb_ = pcl + (MI*16 + 4*g)*12; \
        a_##MI##_0 *= geval4(qb_, x0_0, x1_0, x02_0, x11_0, x12_0); \
        a_##MI##_1 *= geval4(qb_, x0_1, x1_1, x02_1, x11_1, x12_1); }
        EPI(0) EPI(1) EPI(2) EPI(3)
#undef EPI

        // rebuild next-layer B-frags in-register (kperm identity)
#define REB(NI) { \
        frag2 tA = mkfrag(a_0_##NI, a_1_##NI); \
        frag2 tB = mkfrag(a_2_##NI, a_3_##NI); \
        fh_##NI##_0 = tA.h; fl_##NI##_0 = tA.l; \
        fh_##NI##_1 = tB.h; fl_##NI##_1 = tB.l; }
        REB(0) REB(1)
#undef REB
    }

    // ---- output: out[o,px] = Wout[o,k] h4[k,px] + out_b ----
    const s16x8 oh0 = *(const s16x8*)(wouthi + lm*64 +      g*8);
    const s16x8 ol0 = *(const s16x8*)(woutlo + lm*64 +      g*8);
    const s16x8 oh1 = *(const s16x8*)(wouthi + lm*64 + 32 + g*8);
    const s16x8 ol1 = *(const s16x8*)(woutlo + lm*64 + 32 + g*8);
    float ob0 = out_b[0], ob1 = out_b[1], ob2 = out_b[2];
#define OUTNI(NI, PO) { \
    f32x4 ao = (f32x4)(0.0f); \
    ao = BMFMA(oh0, fh_##NI##_0, ao, 0, 0, 0); \
    ao = BMFMA(oh0, fl_##NI##_0, ao, 0, 0, 0); \
    ao = BMFMA(ol0, fh_##NI##_0, ao, 0, 0, 0); \
    ao = BMFMA(oh1, fh_##NI##_1, ao, 0, 0, 0); \
    ao = BMFMA(oh1, fl_##NI##_1, ao, 0, 0, 0); \
    ao = BMFMA(ol1, fh_##NI##_1, ao, 0, 0, 0); \
    if (lane < 16) { \
        float* po = out + PO; \
        po[0]     = ao[0] + ob0; \
        po[HW2]   = ao[1] + ob1; \
        po[2*HW2] = ao[2] + ob2; } }
    OUTNI(0, pixo0) OUTNI(1, pixo1)
#undef OUTNI
#undef BMFMA
}

extern "C" void kernel_launch(void* const* d_in, const int* in_sizes, int n_in,
                              void* d_out, int out_size, void* d_ws, size_t ws_size,
                              hipStream_t stream) {
    const float* x      = (const float*)d_in[0];
    const float* filt_w = (const float*)d_in[1];
    const float* filt_b = (const float*)d_in[2];
    const float* mu     = (const float*)d_in[3];
    const float* gamma  = (const float*)d_in[4];
    const float* theta  = (const float*)d_in[5];
    const float* lin_w  = (const float*)d_in[6];
    const float* lin_b  = (const float*)d_in[7];
    const float* out_w  = (const float*)d_in[8];
    const float* out_b  = (const float*)d_in[9];

    char* ws = (char*)d_ws;
    float*    pcq    = (float*)ws;
    ushort_t* whi    = (ushort_t*)(ws + WS_WHI);
    ushort_t* wlo    = (ushort_t*)(ws + WS_WLO);
    ushort_t* wouthi = (ushort_t*)(ws + WS_WOH);
    ushort_t* woutlo = (ushort_t*)(ws + WS_WOL);

    gabor_pre<<<70, 256, 0, stream>>>(filt_w, filt_b, mu, gamma, theta,
                                      lin_w, out_w, pcq, whi, wlo, wouthi, woutlo);
    gabor_mfma<<<4096, 256, 0, stream>>>(x, lin_b, out_b, pcq, whi, wlo,
                                         wouthi, woutlo, (float*)d_out);
}

// Round 13
// 141.703 us; speedup vs baseline: 1.6536x; 1.5634x over previous
//
#include <hip/hip_runtime.h>
#include <hip/hip_bf16.h>
#include <math.h>

#define HW2 262144              // 512*512
#define TWO_PI     6.28318530717958647693f
#define INV_TWO_PI 0.15915494309189533577f
#define LOG2E      1.44269504088896340736f

typedef float  f32x4  __attribute__((ext_vector_type(4)));
typedef short  s16x8  __attribute__((ext_vector_type(8)));
typedef unsigned short ushort_t;

__device__ __forceinline__ ushort_t bf16_hi(float v) {
    __hip_bfloat16 h = __float2bfloat16(v);
    return __builtin_bit_cast(ushort_t, h);
}
__device__ __forceinline__ float bf16_tof(ushort_t u) {
    unsigned int x = ((unsigned int)u) << 16;
    return __builtin_bit_cast(float, x);
}

// k-slot permutation (verified R7/R8, absmax 6.1e-5): stored k-slot
// (KC*32 + g*8 + j) holds source channel KC*32 + (j>>2)*16 + g*4 + (j&3).
// With W columns stored in this order, next-layer B-frag elem j of chunk KC
// at lane-group g equals acc[2KC + (j>>2)][j&3] ON THE SAME LANE ->
// no LDS / shuffle / barrier relayout between layers.
__device__ __forceinline__ int kperm(int ks) {
    int KC = ks >> 5, g = (ks >> 3) & 3, j = ks & 7;
    return KC * 32 + (j >> 2) * 16 + g * 4 + (j & 3);
}

// ---- ws layout (bytes) ----
// pcq    f32[5][64][12] @ 0      expanded gabor constants
//   per channel: [a,b,c,d, e,f,w0r,w1r, br,0,0,0]
// whi    u16[4][64][64] @ 15360  lin_w hi-bf16, [c_out][k_perm]
// wlo    u16[4][64][64] @ 48128  lin_w lo-bf16
// wouthi u16[16][64]    @ 80896  out_w hi (rows 3..15 zero), k_perm cols
// woutlo u16[16][64]    @ 82944
#define WS_WHI  15360
#define WS_WLO  48128
#define WS_WOH  80896
#define WS_WOL  82944

__global__ void gabor_pre(const float* __restrict__ filt_w,
                          const float* __restrict__ filt_b,
                          const float* __restrict__ mu,
                          const float* __restrict__ gamma,
                          const float* __restrict__ theta,
                          const float* __restrict__ lin_w,
                          const float* __restrict__ out_w,
                          float* __restrict__ pcq,
                          ushort_t* __restrict__ whi, ushort_t* __restrict__ wlo,
                          ushort_t* __restrict__ wouthi, ushort_t* __restrict__ woutlo) {
    int t = blockIdx.x * 256 + threadIdx.x;
    if (t < 320) {
        int i = t;
        float ang = TWO_PI * theta[i];
        float cs = cosf(ang), sn = sinf(ang);
        float g0 = gamma[i*2+0], g1 = gamma[i*2+1];
        float g0s = g0*g0, g1s = g1*g1;
        float cs2 = cs*cs, sn2 = sn*sn;
        float A = -0.5f * LOG2E * (g0s*cs2 + g1s*sn2);
        float B = -LOG2E * (cs*sn*(g0s - g1s));
        float C = -0.5f * LOG2E * (g0s*sn2 + g1s*cs2);
        float m0 = mu[i*2+0], m1 = mu[i*2+1];
        float* o = pcq + i*12;
        o[0] = A;  o[1] = B;  o[2] = C;
        o[3] = -(2.0f*A*m0 + B*m1);
        o[4] = -(B*m0 + 2.0f*C*m1);
        o[5] = A*m0*m0 + B*m0*m1 + C*m1*m1;
        o[6] = filt_w[i*2+0] * INV_TWO_PI;
        o[7] = filt_w[i*2+1] * INV_TWO_PI;
        o[8] = filt_b[i] * INV_TWO_PI;
        o[9] = 0.0f; o[10] = 0.0f; o[11] = 0.0f;
    } else if (t < 320 + 16384) {
        int i  = t - 320;                      // l*4096 + c*64 + ks
        int ks = i & 63;
        float w = lin_w[(i - ks) + kperm(ks)];
        ushort_t h = bf16_hi(w);
        whi[i] = h;
        wlo[i] = bf16_hi(w - bf16_tof(h));
    } else if (t < 320 + 16384 + 1024) {
        int i  = t - (320 + 16384);            // m*64 + ks
        int m  = i >> 6, ks = i & 63;
        float w = (m < 3) ? out_w[m*64 + kperm(ks)] : 0.0f;
        ushort_t h = bf16_hi(w);
        wouthi[i] = h;
        woutlo[i] = bf16_hi(w - bf16_tof(h));
    }
}

// expanded gabor eval (x02,x11,x12 shared per pixel)
// NUMERICS NOTE (R11/R12 erratum): this exact right-to-left fmaf chain is
// load-bearing. The packed f32x2 left-to-right sum version failed at
// 3.7-4.0e-2 absmax (1200 output-ulps vs 2 here) — the reassociated
// roundings in the cancellation-prone expanded quadratic amplify through
// 5 multiplicative gabor factors x layer gains. Do not reassociate.
__device__ __forceinline__ float gevalp(const float* __restrict__ q,
                                        float x0, float x1,
                                        float x02, float x11, float x12) {
    f32x4 qa = *(const f32x4*)q;
    f32x4 qb = *(const f32x4*)(q + 4);
    float t = fmaf(qa[0], x02, fmaf(qa[1], x11,
              fmaf(qa[2], x12, fmaf(qa[3], x0, fmaf(qb[0], x1, qb[1])))));
    float e  = __builtin_amdgcn_exp2f(t);
    float sa = fmaf(qb[2], x0, fmaf(qb[3], x1, q[8]));
    return e * __builtin_amdgcn_sinf(sa);
}

// 4 consecutive channels starting at q (stride 12 floats)
__device__ __forceinline__ f32x4 geval4(const float* __restrict__ q,
                                        float x0, float x1,
                                        float x02, float x11, float x12) {
    f32x4 r;
    r[0] = gevalp(q,      x0, x1, x02, x11, x12);
    r[1] = gevalp(q + 12, x0, x1, x02, x11, x12);
    r[2] = gevalp(q + 24, x0, x1, x02, x11, x12);
    r[3] = gevalp(q + 36, x0, x1, x02, x11, x12);
    return r;
}

struct frag2 { s16x8 h, l; };
// build B-frag pair (hi/lo) from two C/D f32x4's (MI even, MI odd).
// RNE hi + RNE residual (R11 erratum: truncated-hi split fails).
__device__ __forceinline__ frag2 mkfrag(f32x4 vA, f32x4 vB) {
    s16x8 fh, fl;
#define MKF_R(R) { \
    ushort_t hA = bf16_hi(vA[R]); ushort_t hB = bf16_hi(vB[R]); \
    fh[R] = (short)hA; fh[R + 4] = (short)hB; \
    fl[R]     = (short)bf16_hi(vA[R] - bf16_tof(hA)); \
    fl[R + 4] = (short)bf16_hi(vB[R] - bf16_tof(hB)); }
    MKF_R(0) MKF_R(1) MKF_R(2) MKF_R(3)
#undef MKF_R
    return {fh, fl};
}

// One wave = 64 pixels (NI=4), 4 independent waves per 256-block. No LDS,
// no barriers, and NO LOCAL ARRAYS: all state is individually named
// variables (R7's arrays were never SROA-promoted -> scratch to HBM).
// This is the R8 configuration — best measured (141 us) after R9-R12
// variants (occupancy bounds, NI=2, packed eval) all regressed or failed.
// GEMM per layer: D[c,px] = W[c,k] h[k,px], mfma_f32_16x16x32_bf16,
// 3-product split-bf16 (ah*bh + ah*bl + al*bh; al*bl ~2^-16 rel dropped).
//   A frag: m = lane&15, k-slot = (lane>>4)*8 + j  (W rows, permuted cols)
//   B frag: n = lane&15 (pixel), k-slot = (lane>>4)*8 + j
//   C/D:    col n = lane&15 (pixel), row m = (lane>>4)*4 + reg (channel)
__global__ __launch_bounds__(256, 2) void gabor_mfma(
    const float* __restrict__ x, const float* __restrict__ lin_b,
    const float* __restrict__ out_b, const float* __restrict__ pcq,
    const ushort_t* __restrict__ whi, const ushort_t* __restrict__ wlo,
    const ushort_t* __restrict__ wouthi, const ushort_t* __restrict__ woutlo,
    float* __restrict__ out) {
    const int lane = threadIdx.x & 63;
    const int wid  = threadIdx.x >> 6;
    const int g    = lane >> 4;
    const int lm   = lane & 15;
    const int base = blockIdx.x * 256 + wid * 64;

    f32x4 x0v, x1v, x02v, x11v, x12v;
    int pixo0, pixo1, pixo2, pixo3;
#define LOADPX(NI) { \
    int P = base + NI*16 + lm; \
    int bb = P >> 18, pix = P & (HW2 - 1); \
    const float* xb = x + bb*(2*HW2) + pix; \
    float a = xb[0], b = xb[HW2]; \
    x0v[NI] = a; x1v[NI] = b; \
    x02v[NI] = a*a; x11v[NI] = a*b; x12v[NI] = b*b; \
    int po = bb*(3*HW2) + pix; \
    if (NI == 0) pixo0 = po; else if (NI == 1) pixo1 = po; \
    else if (NI == 2) pixo2 = po; else pixo3 = po; }
    LOADPX(0) LOADPX(1) LOADPX(2) LOADPX(3)
#undef LOADPX

    // h as B-fragments: fh_<ni>_<kc> / fl_<ni>_<kc>, all named (no arrays)
    s16x8 fh_0_0, fh_0_1, fh_1_0, fh_1_1, fh_2_0, fh_2_1, fh_3_0, fh_3_1;
    s16x8 fl_0_0, fl_0_1, fl_1_0, fl_1_1, fl_2_0, fl_2_1, fl_3_0, fl_3_1;

    // ---- layer 0: gabor at C/D positions, straight into frags ----
#define L0(NI) { \
    f32x4 v0 = geval4(pcq + (4*g)*12,      x0v[NI], x1v[NI], x02v[NI], x11v[NI], x12v[NI]); \
    f32x4 v1 = geval4(pcq + (16 + 4*g)*12, x0v[NI], x1v[NI], x02v[NI], x11v[NI], x12v[NI]); \
    f32x4 v2 = geval4(pcq + (32 + 4*g)*12, x0v[NI], x1v[NI], x02v[NI], x11v[NI], x12v[NI]); \
    f32x4 v3 = geval4(pcq + (48 + 4*g)*12, x0v[NI], x1v[NI], x02v[NI], x11v[NI], x12v[NI]); \
    frag2 tA = mkfrag(v0, v1); frag2 tB = mkfrag(v2, v3); \
    fh_##NI##_0 = tA.h; fl_##NI##_0 = tA.l; \
    fh_##NI##_1 = tB.h; fl_##NI##_1 = tB.l; }
    L0(0) L0(1) L0(2) L0(3)
#undef L0

#define BMFMA __builtin_amdgcn_mfma_f32_16x16x32_bf16
    // ---- layers 1..4 ----
#pragma unroll 1
    for (int l = 1; l <= 4; ++l) {
        const ushort_t* whl = whi + (l-1)*4096;
        const ushort_t* wll = wlo + (l-1)*4096;
        const float*    bv  = lin_b + (l-1)*64;
        const float*    pcl = pcq + l*768;

        f32x4 bb0 = *(const f32x4*)(bv +      4*g);
        f32x4 bb1 = *(const f32x4*)(bv + 16 + 4*g);
        f32x4 bb2 = *(const f32x4*)(bv + 32 + 4*g);
        f32x4 bb3 = *(const f32x4*)(bv + 48 + 4*g);
        f32x4 a_0_0 = bb0, a_0_1 = bb0, a_0_2 = bb0, a_0_3 = bb0;
        f32x4 a_1_0 = bb1, a_1_1 = bb1, a_1_2 = bb1, a_1_3 = bb1;
        f32x4 a_2_0 = bb2, a_2_1 = bb2, a_2_2 = bb2, a_2_3 = bb2;
        f32x4 a_3_0 = bb3, a_3_1 = bb3, a_3_2 = bb3, a_3_3 = bb3;

        // each W fragment pair feeds all 4 pixel tiles (12 MFMAs per load)
#define MSTEP(KC, MI) { \
        const s16x8 ah = *(const s16x8*)(whl + (MI*16 + lm)*64 + KC*32 + g*8); \
        const s16x8 al = *(const s16x8*)(wll + (MI*16 + lm)*64 + KC*32 + g*8); \
        a_##MI##_0 = BMFMA(ah, fh_0_##KC, a_##MI##_0, 0, 0, 0); \
        a_##MI##_0 = BMFMA(ah, fl_0_##KC, a_##MI##_0, 0, 0, 0); \
        a_##MI##_0 = BMFMA(al, fh_0_##KC, a_##MI##_0, 0, 0, 0); \
        a_##MI##_1 = BMFMA(ah, fh_1_##KC, a_##MI##_1, 0, 0, 0); \
        a_##MI##_1 = BMFMA(ah, fl_1_##KC, a_##MI##_1, 0, 0, 0); \
        a_##MI##_1 = BMFMA(al, fh_1_##KC, a_##MI##_1, 0, 0, 0); \
        a_##MI##_2 = BMFMA(ah, fh_2_##KC, a_##MI##_2, 0, 0, 0); \
        a_##MI##_2 = BMFMA(ah, fl_2_##KC, a_##MI##_2, 0, 0, 0); \
        a_##MI##_2 = BMFMA(al, fh_2_##KC, a_##MI##_2, 0, 0, 0); \
        a_##MI##_3 = BMFMA(ah, fh_3_##KC, a_##MI##_3, 0, 0, 0); \
        a_##MI##_3 = BMFMA(ah, fl_3_##KC, a_##MI##_3, 0, 0, 0); \
        a_##MI##_3 = BMFMA(al, fh_3_##KC, a_##MI##_3, 0, 0, 0); }
        MSTEP(0, 0) MSTEP(0, 1) MSTEP(0, 2) MSTEP(0, 3)
        MSTEP(1, 0) MSTEP(1, 1) MSTEP(1, 2) MSTEP(1, 3)
#undef MSTEP

        // epilogue: acc *= gabor (params CSE'd across the 4 pixel tiles)
#define EPI(MI) { \
        const float* qb_ = pcl + (MI*16 + 4*g)*12; \
        a_##MI##_0 *= geval4(qb_, x0v[0], x1v[0], x02v[0], x11v[0], x12v[0]); \
        a_##MI##_1 *= geval4(qb_, x0v[1], x1v[1], x02v[1], x11v[1], x12v[1]); \
        a_##MI##_2 *= geval4(qb_, x0v[2], x1v[2], x02v[2], x11v[2], x12v[2]); \
        a_##MI##_3 *= geval4(qb_, x0v[3], x1v[3], x02v[3], x11v[3], x12v[3]); }
        EPI(0) EPI(1) EPI(2) EPI(3)
#undef EPI

        // rebuild next-layer B-frags in-register (kperm identity)
#define REB(NI) { \
        frag2 tA = mkfrag(a_0_##NI, a_1_##NI); \
        frag2 tB = mkfrag(a_2_##NI, a_3_##NI); \
        fh_##NI##_0 = tA.h; fl_##NI##_0 = tA.l; \
        fh_##NI##_1 = tB.h; fl_##NI##_1 = tB.l; }
        REB(0) REB(1) REB(2) REB(3)
#undef REB
    }

    // ---- output: out[o,px] = Wout[o,k] h4[k,px] + out_b ----
    const s16x8 oh0 = *(const s16x8*)(wouthi + lm*64 +      g*8);
    const s16x8 ol0 = *(const s16x8*)(woutlo + lm*64 +      g*8);
    const s16x8 oh1 = *(const s16x8*)(wouthi + lm*64 + 32 + g*8);
    const s16x8 ol1 = *(const s16x8*)(woutlo + lm*64 + 32 + g*8);
    float ob0 = out_b[0], ob1 = out_b[1], ob2 = out_b[2];
#define OUTNI(NI, PO) { \
    f32x4 ao = (f32x4)(0.0f); \
    ao = BMFMA(oh0, fh_##NI##_0, ao, 0, 0, 0); \
    ao = BMFMA(oh0, fl_##NI##_0, ao, 0, 0, 0); \
    ao = BMFMA(ol0, fh_##NI##_0, ao, 0, 0, 0); \
    ao = BMFMA(oh1, fh_##NI##_1, ao, 0, 0, 0); \
    ao = BMFMA(oh1, fl_##NI##_1, ao, 0, 0, 0); \
    ao = BMFMA(ol1, fh_##NI##_1, ao, 0, 0, 0); \
    if (lane < 16) { \
        float* po = out + PO; \
        po[0]     = ao[0] + ob0; \
        po[HW2]   = ao[1] + ob1; \
        po[2*HW2] = ao[2] + ob2; } }
    OUTNI(0, pixo0) OUTNI(1, pixo1) OUTNI(2, pixo2) OUTNI(3, pixo3)
#undef OUTNI
#undef BMFMA
}

extern "C" void kernel_launch(void* const* d_in, const int* in_sizes, int n_in,
                              void* d_out, int out_size, void* d_ws, size_t ws_size,
                              hipStream_t stream) {
    const float* x      = (const float*)d_in[0];
    const float* filt_w = (const float*)d_in[1];
    const float* filt_b = (const float*)d_in[2];
    const float* mu     = (const float*)d_in[3];
    const float* gamma  = (const float*)d_in[4];
    const float* theta  = (const float*)d_in[5];
    const float* lin_w  = (const float*)d_in[6];
    const float* lin_b  = (const float*)d_in[7];
    const float* out_w  = (const float*)d_in[8];
    const float* out_b  = (const float*)d_in[9];

    char* ws = (char*)d_ws;
    float*    pcq    = (float*)ws;
    ushort_t* whi    = (ushort_t*)(ws + WS_WHI);
    ushort_t* wlo    = (ushort_t*)(ws + WS_WLO);
    ushort_t* wouthi = (ushort_t*)(ws + WS_WOH);
    ushort_t* woutlo = (ushort_t*)(ws + WS_WOL);

    gabor_pre<<<70, 256, 0, stream>>>(filt_w, filt_b, mu, gamma, theta,
                                      lin_w, out_w, pcq, whi, wlo, wouthi, woutlo);
    gabor_mfma<<<2048, 256, 0, stream>>>(x, lin_b, out_b, pcq, whi, wlo,
                                         wouthi, woutlo, (float*)d_out);
}

// Round 14
// 141.484 us; speedup vs baseline: 1.6561x; 1.0015x over previous
//
#include <hip/hip_runtime.h>
#include <hip/hip_bf16.h>
#include <math.h>

#define HW2 262144              // 512*512
#define TWO_PI     6.28318530717958647693f
#define INV_TWO_PI 0.15915494309189533577f
#define LOG2E      1.44269504088896340736f

typedef float  f32x4  __attribute__((ext_vector_type(4)));
typedef short  s16x8  __attribute__((ext_vector_type(8)));
typedef __bf16 bf16x8 __attribute__((ext_vector_type(8)));
typedef unsigned short ushort_t;

__device__ __forceinline__ ushort_t bf16_hi(float v) {
    __hip_bfloat16 h = __float2bfloat16(v);
    return __builtin_bit_cast(ushort_t, h);
}
__device__ __forceinline__ float bf16_tof(ushort_t u) {
    unsigned int x = ((unsigned int)u) << 16;
    return __builtin_bit_cast(float, x);
}

// k-slot permutation (verified R7/R8, absmax 6.1e-5): stored k-slot
// (KC*32 + g*8 + j) holds source channel KC*32 + (j>>2)*16 + g*4 + (j&3).
// With W columns stored in this order, next-layer B-frag elem j of chunk KC
// at lane-group g equals acc[2KC + (j>>2)][j&3] ON THE SAME LANE ->
// no LDS / shuffle / barrier relayout between layers.
__device__ __forceinline__ int kperm(int ks) {
    int KC = ks >> 5, g = (ks >> 3) & 3, j = ks & 7;
    return KC * 32 + (j >> 2) * 16 + g * 4 + (j & 3);
}

// ---- ws layout (bytes) ----
// pcq    f32[5][64][12] @ 0      expanded gabor constants
//   per channel: [a,b,c,d, e,f,w0r,w1r, br,0,0,0]
// whi    u16[4][64][64] @ 15360  lin_w hi-bf16, [c_out][k_perm]
// wlo    u16[4][64][64] @ 48128  lin_w lo-bf16
// wouthi u16[16][64]    @ 80896  out_w hi (rows 3..15 zero), k_perm cols
// woutlo u16[16][64]    @ 82944
#define WS_WHI  15360
#define WS_WLO  48128
#define WS_WOH  80896
#define WS_WOL  82944

__global__ void gabor_pre(const float* __restrict__ filt_w,
                          const float* __restrict__ filt_b,
                          const float* __restrict__ mu,
                          const float* __restrict__ gamma,
                          const float* __restrict__ theta,
                          const float* __restrict__ lin_w,
                          const float* __restrict__ out_w,
                          float* __restrict__ pcq,
                          ushort_t* __restrict__ whi, ushort_t* __restrict__ wlo,
                          ushort_t* __restrict__ wouthi, ushort_t* __restrict__ woutlo) {
    int t = blockIdx.x * 256 + threadIdx.x;
    if (t < 320) {
        int i = t;
        float ang = TWO_PI * theta[i];
        float cs = cosf(ang), sn = sinf(ang);
        float g0 = gamma[i*2+0], g1 = gamma[i*2+1];
        float g0s = g0*g0, g1s = g1*g1;
        float cs2 = cs*cs, sn2 = sn*sn;
        float A = -0.5f * LOG2E * (g0s*cs2 + g1s*sn2);
        float B = -LOG2E * (cs*sn*(g0s - g1s));
        float C = -0.5f * LOG2E * (g0s*sn2 + g1s*cs2);
        float m0 = mu[i*2+0], m1 = mu[i*2+1];
        float* o = pcq + i*12;
        o[0] = A;  o[1] = B;  o[2] = C;
        o[3] = -(2.0f*A*m0 + B*m1);
        o[4] = -(B*m0 + 2.0f*C*m1);
        o[5] = A*m0*m0 + B*m0*m1 + C*m1*m1;
        o[6] = filt_w[i*2+0] * INV_TWO_PI;
        o[7] = filt_w[i*2+1] * INV_TWO_PI;
        o[8] = filt_b[i] * INV_TWO_PI;
        o[9] = 0.0f; o[10] = 0.0f; o[11] = 0.0f;
    } else if (t < 320 + 16384) {
        int i  = t - 320;                      // l*4096 + c*64 + ks
        int ks = i & 63;
        float w = lin_w[(i - ks) + kperm(ks)];
        ushort_t h = bf16_hi(w);
        whi[i] = h;
        wlo[i] = bf16_hi(w - bf16_tof(h));
    } else if (t < 320 + 16384 + 1024) {
        int i  = t - (320 + 16384);            // m*64 + ks
        int m  = i >> 6, ks = i & 63;
        float w = (m < 3) ? out_w[m*64 + kperm(ks)] : 0.0f;
        ushort_t h = bf16_hi(w);
        wouthi[i] = h;
        woutlo[i] = bf16_hi(w - bf16_tof(h));
    }
}

// expanded gabor eval (x02,x11,x12 shared per pixel)
// NUMERICS NOTE (R11/R12 erratum): this exact right-to-left fmaf chain is
// load-bearing. The packed f32x2 left-to-right sum version failed at
// 3.7-4.0e-2 absmax — do not reassociate.
__device__ __forceinline__ float gevalp(const float* __restrict__ q,
                                        float x0, float x1,
                                        float x02, float x11, float x12) {
    f32x4 qa = *(const f32x4*)q;
    f32x4 qb = *(const f32x4*)(q + 4);
    float t = fmaf(qa[0], x02, fmaf(qa[1], x11,
              fmaf(qa[2], x12, fmaf(qa[3], x0, fmaf(qb[0], x1, qb[1])))));
    float e  = __builtin_amdgcn_exp2f(t);
    float sa = fmaf(qb[2], x0, fmaf(qb[3], x1, q[8]));
    return e * __builtin_amdgcn_sinf(sa);
}

// 4 consecutive channels starting at q (stride 12 floats)
__device__ __forceinline__ f32x4 geval4(const float* __restrict__ q,
                                        float x0, float x1,
                                        float x02, float x11, float x12) {
    f32x4 r;
    r[0] = gevalp(q,      x0, x1, x02, x11, x12);
    r[1] = gevalp(q + 12, x0, x1, x02, x11, x12);
    r[2] = gevalp(q + 24, x0, x1, x02, x11, x12);
    r[3] = gevalp(q + 36, x0, x1, x02, x11, x12);
    return r;
}

struct frag2 { s16x8 h, l; };
// build B-frag pair (hi/lo) from two C/D f32x4's (MI even, MI odd).
// R14: native __bf16 ext-vector build. (__bf16)f32 = fptrunc RNE =
// bit-identical to __float2bfloat16; (float)__bf16 = fpext (shl16) =
// bit-identical to bf16_tof. The 8-wide bf16 build_vector from fptrunc
// pairs is the canonical v_cvt_pk_bf16_f32 pattern — replaces scalar
// cvts + sub-dword <8 x i16> insert merge chains (R8-R13 pack cost).
// Values are IDENTICAL to R8's mkfrag; only packing mechanics change.
__device__ __forceinline__ frag2 mkfrag(f32x4 vA, f32x4 vB) {
    bf16x8 h, l;
    h[0] = (__bf16)vA[0]; h[1] = (__bf16)vA[1];
    h[2] = (__bf16)vA[2]; h[3] = (__bf16)vA[3];
    h[4] = (__bf16)vB[0]; h[5] = (__bf16)vB[1];
    h[6] = (__bf16)vB[2]; h[7] = (__bf16)vB[3];
    l[0] = (__bf16)(vA[0] - (float)h[0]);
    l[1] = (__bf16)(vA[1] - (float)h[1]);
    l[2] = (__bf16)(vA[2] - (float)h[2]);
    l[3] = (__bf16)(vA[3] - (float)h[3]);
    l[4] = (__bf16)(vB[0] - (float)h[4]);
    l[5] = (__bf16)(vB[1] - (float)h[5]);
    l[6] = (__bf16)(vB[2] - (float)h[6]);
    l[7] = (__bf16)(vB[3] - (float)h[7]);
    frag2 r;
    r.h = __builtin_bit_cast(s16x8, h);
    r.l = __builtin_bit_cast(s16x8, l);
    return r;
}

// One wave = 64 pixels (NI=4), 4 independent waves per 256-block. No LDS,
// no barriers, and NO LOCAL ARRAYS: all state is individually named
// variables (R7's arrays were never SROA-promoted -> scratch to HBM).
// R8 configuration (best measured, 141 us) + R14 mkfrag pack rewrite.
// GEMM per layer: D[c,px] = W[c,k] h[k,px], mfma_f32_16x16x32_bf16,
// 3-product split-bf16 (ah*bh + ah*bl + al*bh; al*bl ~2^-16 rel dropped).
//   A frag: m = lane&15, k-slot = (lane>>4)*8 + j  (W rows, permuted cols)
//   B frag: n = lane&15 (pixel), k-slot = (lane>>4)*8 + j
//   C/D:    col n = lane&15 (pixel), row m = (lane>>4)*4 + reg (channel)
__global__ __launch_bounds__(256, 2) void gabor_mfma(
    const float* __restrict__ x, const float* __restrict__ lin_b,
    const float* __restrict__ out_b, const float* __restrict__ pcq,
    const ushort_t* __restrict__ whi, const ushort_t* __restrict__ wlo,
    const ushort_t* __restrict__ wouthi, const ushort_t* __restrict__ woutlo,
    float* __restrict__ out) {
    const int lane = threadIdx.x & 63;
    const int wid  = threadIdx.x >> 6;
    const int g    = lane >> 4;
    const int lm   = lane & 15;
    const int base = blockIdx.x * 256 + wid * 64;

    f32x4 x0v, x1v, x02v, x11v, x12v;
    int pixo0, pixo1, pixo2, pixo3;
#define LOADPX(NI) { \
    int P = base + NI*16 + lm; \
    int bb = P >> 18, pix = P & (HW2 - 1); \
    const float* xb = x + bb*(2*HW2) + pix; \
    float a = xb[0], b = xb[HW2]; \
    x0v[NI] = a; x1v[NI] = b; \
    x02v[NI] = a*a; x11v[NI] = a*b; x12v[NI] = b*b; \
    int po = bb*(3*HW2) + pix; \
    if (NI == 0) pixo0 = po; else if (NI == 1) pixo1 = po; \
    else if (NI == 2) pixo2 = po; else pixo3 = po; }
    LOADPX(0) LOADPX(1) LOADPX(2) LOADPX(3)
#undef LOADPX

    // h as B-fragments: fh_<ni>_<kc> / fl_<ni>_<kc>, all named (no arrays)
    s16x8 fh_0_0, fh_0_1, fh_1_0, fh_1_1, fh_2_0, fh_2_1, fh_3_0, fh_3_1;
    s16x8 fl_0_0, fl_0_1, fl_1_0, fl_1_1, fl_2_0, fl_2_1, fl_3_0, fl_3_1;

    // ---- layer 0: gabor at C/D positions, straight into frags ----
#define L0(NI) { \
    f32x4 v0 = geval4(pcq + (4*g)*12,      x0v[NI], x1v[NI], x02v[NI], x11v[NI], x12v[NI]); \
    f32x4 v1 = geval4(pcq + (16 + 4*g)*12, x0v[NI], x1v[NI], x02v[NI], x11v[NI], x12v[NI]); \
    f32x4 v2 = geval4(pcq + (32 + 4*g)*12, x0v[NI], x1v[NI], x02v[NI], x11v[NI], x12v[NI]); \
    f32x4 v3 = geval4(pcq + (48 + 4*g)*12, x0v[NI], x1v[NI], x02v[NI], x11v[NI], x12v[NI]); \
    frag2 tA = mkfrag(v0, v1); frag2 tB = mkfrag(v2, v3); \
    fh_##NI##_0 = tA.h; fl_##NI##_0 = tA.l; \
    fh_##NI##_1 = tB.h; fl_##NI##_1 = tB.l; }
    L0(0) L0(1) L0(2) L0(3)
#undef L0

#define BMFMA __builtin_amdgcn_mfma_f32_16x16x32_bf16
    // ---- layers 1..4 ----
#pragma unroll 1
    for (int l = 1; l <= 4; ++l) {
        const ushort_t* whl = whi + (l-1)*4096;
        const ushort_t* wll = wlo + (l-1)*4096;
        const float*    bv  = lin_b + (l-1)*64;
        const float*    pcl = pcq + l*768;

        f32x4 bb0 = *(const f32x4*)(bv +      4*g);
        f32x4 bb1 = *(const f32x4*)(bv + 16 + 4*g);
        f32x4 bb2 = *(const f32x4*)(bv + 32 + 4*g);
        f32x4 bb3 = *(const f32x4*)(bv + 48 + 4*g);
        f32x4 a_0_0 = bb0, a_0_1 = bb0, a_0_2 = bb0, a_0_3 = bb0;
        f32x4 a_1_0 = bb1, a_1_1 = bb1, a_1_2 = bb1, a_1_3 = bb1;
        f32x4 a_2_0 = bb2, a_2_1 = bb2, a_2_2 = bb2, a_2_3 = bb2;
        f32x4 a_3_0 = bb3, a_3_1 = bb3, a_3_2 = bb3, a_3_3 = bb3;

        // each W fragment pair feeds all 4 pixel tiles (12 MFMAs per load)
#define MSTEP(KC, MI) { \
        const s16x8 ah = *(const s16x8*)(whl + (MI*16 + lm)*64 + KC*32 + g*8); \
        const s16x8 al = *(const s16x8*)(wll + (MI*16 + lm)*64 + KC*32 + g*8); \
        a_##MI##_0 = BMFMA(ah, fh_0_##KC, a_##MI##_0, 0, 0, 0); \
        a_##MI##_0 = BMFMA(ah, fl_0_##KC, a_##MI##_0, 0, 0, 0); \
        a_##MI##_0 = BMFMA(al, fh_0_##KC, a_##MI##_0, 0, 0, 0); \
        a_##MI##_1 = BMFMA(ah, fh_1_##KC, a_##MI##_1, 0, 0, 0); \
        a_##MI##_1 = BMFMA(ah, fl_1_##KC, a_##MI##_1, 0, 0, 0); \
        a_##MI##_1 = BMFMA(al, fh_1_##KC, a_##MI##_1, 0, 0, 0); \
        a_##MI##_2 = BMFMA(ah, fh_2_##KC, a_##MI##_2, 0, 0, 0); \
        a_##MI##_2 = BMFMA(ah, fl_2_##KC, a_##MI##_2, 0, 0, 0); \
        a_##MI##_2 = BMFMA(al, fh_2_##KC, a_##MI##_2, 0, 0, 0); \
        a_##MI##_3 = BMFMA(ah, fh_3_##KC, a_##MI##_3, 0, 0, 0); \
        a_##MI##_3 = BMFMA(ah, fl_3_##KC, a_##MI##_3, 0, 0, 0); \
        a_##MI##_3 = BMFMA(al, fh_3_##KC, a_##MI##_3, 0, 0, 0); }
        MSTEP(0, 0) MSTEP(0, 1) MSTEP(0, 2) MSTEP(0, 3)
        MSTEP(1, 0) MSTEP(1, 1) MSTEP(1, 2) MSTEP(1, 3)
#undef MSTEP

        // epilogue: acc *= gabor (params CSE'd across the 4 pixel tiles)
#define EPI(MI) { \
        const float* qb_ = pcl + (MI*16 + 4*g)*12; \
        a_##MI##_0 *= geval4(qb_, x0v[0], x1v[0], x02v[0], x11v[0], x12v[0]); \
        a_##MI##_1 *= geval4(qb_, x0v[1], x1v[1], x02v[1], x11v[1], x12v[1]); \
        a_##MI##_2 *= geval4(qb_, x0v[2], x1v[2], x02v[2], x11v[2], x12v[2]); \
        a_##MI##_3 *= geval4(qb_, x0v[3], x1v[3], x02v[3], x11v[3], x12v[3]); }
        EPI(0) EPI(1) EPI(2) EPI(3)
#undef EPI

        // rebuild next-layer B-frags in-register (kperm identity)
#define REB(NI) { \
        frag2 tA = mkfrag(a_0_##NI, a_1_##NI); \
        frag2 tB = mkfrag(a_2_##NI, a_3_##NI); \
        fh_##NI##_0 = tA.h; fl_##NI##_0 = tA.l; \
        fh_##NI##_1 = tB.h; fl_##NI##_1 = tB.l; }
        REB(0) REB(1) REB(2) REB(3)
#undef REB
    }

    // ---- output: out[o,px] = Wout[o,k] h4[k,px] + out_b ----
    const s16x8 oh0 = *(const s16x8*)(wouthi + lm*64 +      g*8);
    const s16x8 ol0 = *(const s16x8*)(woutlo + lm*64 +      g*8);
    const s16x8 oh1 = *(const s16x8*)(wouthi + lm*64 + 32 + g*8);
    const s16x8 ol1 = *(const s16x8*)(woutlo + lm*64 + 32 + g*8);
    float ob0 = out_b[0], ob1 = out_b[1], ob2 = out_b[2];
#define OUTNI(NI, PO) { \
    f32x4 ao = (f32x4)(0.0f); \
    ao = BMFMA(oh0, fh_##NI##_0, ao, 0, 0, 0); \
    ao = BMFMA(oh0, fl_##NI##_0, ao, 0, 0, 0); \
    ao = BMFMA(ol0, fh_##NI##_0, ao, 0, 0, 0); \
    ao = BMFMA(oh1, fh_##NI##_1, ao, 0, 0, 0); \
    ao = BMFMA(oh1, fl_##NI##_1, ao, 0, 0, 0); \
    ao = BMFMA(ol1, fh_##NI##_1, ao, 0, 0, 0); \
    if (lane < 16) { \
        float* po = out + PO; \
        po[0]     = ao[0] + ob0; \
        po[HW2]   = ao[1] + ob1; \
        po[2*HW2] = ao[2] + ob2; } }
    OUTNI(0, pixo0) OUTNI(1, pixo1) OUTNI(2, pixo2) OUTNI(3, pixo3)
#undef OUTNI
#undef BMFMA
}

extern "C" void kernel_launch(void* const* d_in, const int* in_sizes, int n_in,
                              void* d_out, int out_size, void* d_ws, size_t ws_size,
                              hipStream_t stream) {
    const float* x      = (const float*)d_in[0];
    const float* filt_w = (const float*)d_in[1];
    const float* filt_b = (const float*)d_in[2];
    const float* mu     = (const float*)d_in[3];
    const float* gamma  = (const float*)d_in[4];
    const float* theta  = (const float*)d_in[5];
    const float* lin_w  = (const float*)d_in[6];
    const float* lin_b  = (const float*)d_in[7];
    const float* out_w  = (const float*)d_in[8];
    const float* out_b  = (const float*)d_in[9];

    char* ws = (char*)d_ws;
    float*    pcq    = (float*)ws;
    ushort_t* whi    = (ushort_t*)(ws + WS_WHI);
    ushort_t* wlo    = (ushort_t*)(ws + WS_WLO);
    ushort_t* wouthi = (ushort_t*)(ws + WS_WOH);
    ushort_t* woutlo = (ushort_t*)(ws + WS_WOL);

    gabor_pre<<<70, 256, 0, stream>>>(filt_w, filt_b, mu, gamma, theta,
                                      lin_w, out_w, pcq, whi, wlo, wouthi, woutlo);
    gabor_mfma<<<2048, 256, 0, stream>>>(x, lin_b, out_b, pcq, whi, wlo,
                                         wouthi, woutlo, (float*)d_out);
}